// Round 6
// baseline (240.763 us; speedup 1.0000x reference)
//
#include <hip/hip_runtime.h>
#include <math.h>

#define NENT 50000
#define RREL 2000
#define AATT 5000
#define EE   400000
#define E2   800000
#define EAE  400000
#define PB   2048   // partials stride per head

__device__ __forceinline__ float leaky(float v){ return v > 0.f ? v : 0.3f * v; }

__device__ __forceinline__ float wave_sum(float v){
#pragma unroll
  for (int m = 32; m; m >>= 1) v += __shfl_xor(v, m);
  return v;
}
__device__ __forceinline__ float wave_max(float v){
#pragma unroll
  for (int m = 32; m; m >>= 1) v = fmaxf(v, __shfl_xor(v, m));
  return v;
}
__device__ __forceinline__ float sum16(float v){
#pragma unroll
  for (int m = 1; m < 16; m <<= 1) v += __shfl_xor(v, m);
  return v;
}
__device__ __forceinline__ float sum8(float v){
#pragma unroll
  for (int m = 1; m < 8; m <<= 1) v += __shfl_xor(v, m);
  return v;
}
// sum the 4 group replicas (lanes differing in bits 4,5)
__device__ __forceinline__ void xreduce4(float4& a, float4& b){
#pragma unroll
  for (int m = 16; m < 64; m <<= 1){
    a.x += __shfl_xor(a.x, m); a.y += __shfl_xor(a.y, m);
    a.z += __shfl_xor(a.z, m); a.w += __shfl_xor(a.w, m);
    b.x += __shfl_xor(b.x, m); b.y += __shfl_xor(b.y, m);
    b.z += __shfl_xor(b.z, m); b.w += __shfl_xor(b.w, m);
  }
}
__device__ __forceinline__ void xreduce4a(float4& a){
#pragma unroll
  for (int m = 16; m < 64; m <<= 1){
    a.x += __shfl_xor(a.x, m); a.y += __shfl_xor(a.y, m);
    a.z += __shfl_xor(a.z, m); a.w += __shfl_xor(a.w, m);
  }
}

__device__ int lowb(const int* a, int n, int key){
  int lo = 0, hi = n;
  while (lo < hi){ int mid = (lo + hi) >> 1; if (a[2 * mid] < key) lo = mid + 1; else hi = mid; }
  return lo;
}

__global__ void k_ptr(const int* ee, const int* er, const int* ea,
                      int* pee, int* per, int* pea){
  int i = blockIdx.x * blockDim.x + threadIdx.x;
  if (i > NENT) return;
  pee[i] = lowb(ee, EE, i);
  per[i] = lowb(er, E2, i);
  pea[i] = lowb(ea, EAE, i);
}

// per-relation/attr scalar tables; HH_l[r] = (hr_h0, hr_h1, hc_h0, hc_h1)
__global__ void k_small(const float* rel_emb, const float* attr_emb,
                        const float* w_r, const float* w_a,
                        const float* eaw, const float* caw,
                        float* h_rel, float* h_attr, float4* HH0, float4* HH1){
  int t = blockIdx.x * blockDim.x + threadIdx.x;
  if (t < RREL){
    const float* e = rel_emb + (size_t)t * 64;
    float s = 0.f;
    for (int k = 0; k < 64; ++k) s += e[k] * w_r[128 + k];
    h_rel[t] = s;
    float hr[4], hc[4];
    for (int lh = 0; lh < 4; ++lh){
      float a = 0.f, c = 0.f;
      for (int k = 0; k < 64; ++k){
        a += e[k] * eaw[lh * 192 + 64 + k];
        c += e[k] * caw[lh * 320 + 128 + k];
      }
      hr[lh] = a; hc[lh] = c;
    }
    HH0[t] = make_float4(hr[0], hr[1], hc[0], hc[1]);
    HH1[t] = make_float4(hr[2], hr[3], hc[2], hc[3]);
  }
  if (t < AATT){
    const float* e = attr_emb + (size_t)t * 64;
    float s = 0.f;
    for (int k = 0; k < 64; ++k) s += e[k] * w_a[128 + k];
    h_attr[t] = s;
  }
}

// GAT concept aggregation. Pass 1: wave-strided online max+sum. Pass 2: 16-lane
// group g owns edge beg+g, beg+g+4, ...; all 16 lanes load the edge/table
// (same-addr, coalesces to 1 request) and compute the weight redundantly —
// NO cross-lane ops in the loop. Lane p (lane&15) owns dims [4p,4p+4).
__device__ float4 concept_agg4(float he, const float* h_tab, const int* idx,
                               int beg, int end, const float* emb, int lane){
  int p = lane & 15, g = lane >> 4;
  float m = -INFINITY, t = 0.f;
  for (int e = beg + lane; e < end; e += 64){
    float v = leaky(he + h_tab[((const int2*)idx)[e].y]);
    float mn = fmaxf(m, v);
    t = t * __expf(m - mn) + __expf(v - mn);
    m = mn;
  }
  float M = wave_max(m);
  float z = wave_sum((t > 0.f) ? t * __expf(m - M) : 0.f);
  float invz = (z > 0.f) ? (1.f / z) : 0.f;
  float4 acc = {0.f, 0.f, 0.f, 0.f};
  for (int e = beg + g; e < end; e += 4){
    int obj = ((const int2*)idx)[e].y;
    float wgt = __expf(leaky(he + h_tab[obj]) - M) * invz;
    float4 f = ((const float4*)(emb + (size_t)obj * 64))[p];
    acc.x = fmaf(wgt, f.x, acc.x); acc.y = fmaf(wgt, f.y, acc.y);
    acc.z = fmaf(wgt, f.z, acc.z); acc.w = fmaf(wgt, f.w, acc.w);
  }
  xreduce4a(acc);
  acc.x = fmaxf(acc.x, 0.f); acc.y = fmaxf(acc.y, 0.f);
  acc.z = fmaxf(acc.z, 0.f); acc.w = fmaxf(acc.w, 0.f);
  return acc;
}

// all row-local per-entity work fused: ent dot tables, both concept GATs,
// mean aggregation, con-attention A/B tables (4 lh), layer-0 u/v tables.
__global__ void k_phase1(const float* ent_emb, const float* rel_emb, const float* attr_emb,
                         const float* w_r, const float* b_r, const float* w_a, const float* b_a,
                         const float* eaw, const float* caw,
                         const int* er_idx, const int* ea_idx, const int* ee,
                         const int* per, const int* pea, const int* pee,
                         const float* h_rel, const float* h_attr,
                         float4* UA0, float4* VB0, float4* UA1, float4* VB1,
                         float* out){
  int w = (blockIdx.x * blockDim.x + threadIdx.x) >> 6;
  int lane = threadIdx.x & 63;
  if (w >= NENT) return;
  int p = lane & 15, g = lane >> 4;
  // her / hea (dot of own ent row with w_r/w_a first 128)
  float2 v = ((const float2*)(ent_emb + (size_t)w * 128))[lane];
  float2 a = ((const float2*)w_r)[lane];
  float2 b = ((const float2*)w_a)[lane];
  float her = wave_sum(v.x * a.x + v.y * a.y);
  float hea = wave_sum(v.x * b.x + v.y * b.y);
  // concept aggregations (dims 4p..4p+4 per lane16, replicated over groups)
  float4 accR = concept_agg4(her + b_r[0], h_rel, er_idx, per[w], per[w + 1], rel_emb, lane);
  float4 accA = concept_agg4(hea + b_a[0], h_attr, ea_idx, pea[w], pea[w + 1], attr_emb, lane);
  if (g == 0){
    ((float4*)(out + (size_t)w * 384 + 256))[p] = accR;
    ((float4*)(out + (size_t)w * 384 + 320))[p] = accA;
    ((float4*)(out + (size_t)NENT * 384 + (size_t)w * 128))[p] = accR;
    ((float4*)(out + (size_t)NENT * 384 + (size_t)w * 128 + 64))[p] = accA;
  }
  // mean neighbor aggregation (512 B ent rows): group-per-edge, no shfl
  int beg = pee[w], end = pee[w + 1];
  float4 mx = {0.f,0.f,0.f,0.f}, my = {0.f,0.f,0.f,0.f};
  for (int e = beg + g; e < end; e += 4){
    int ce = ((const int2*)ee)[e].y;
    const float4* r = (const float4*)(ent_emb + (size_t)ce * 128);
    float4 f0 = r[2 * p], f1 = r[2 * p + 1];
    mx.x += f0.x; mx.y += f0.y; mx.z += f0.z; mx.w += f0.w;
    my.x += f1.x; my.y += f1.y; my.z += f1.z; my.w += f1.w;
  }
  xreduce4(mx, my);
  float invd = 1.f / fmaxf((float)(end - beg), 1.f);
  mx.x *= invd; mx.y *= invd; mx.z *= invd; mx.w *= invd;
  my.x *= invd; my.y *= invd; my.z *= invd; my.w *= invd;
  if (g == 0){
    ((float4*)(out + (size_t)w * 384 + 128))[2 * p]     = mx;
    ((float4*)(out + (size_t)w * 384 + 128))[2 * p + 1] = my;
  }
  // con-attention tables A (row) / B (col) for all 4 (l,h)
#pragma unroll
  for (int lh = 0; lh < 4; ++lh){
    const float* cw = caw + lh * 320;
    float4 c0 = *(const float4*)(cw + 4 * p);
    float4 c1 = *(const float4*)(cw + 64 + 4 * p);
    float4 c2 = *(const float4*)(cw + 192 + 4 * p);
    float4 c3 = *(const float4*)(cw + 256 + 4 * p);
    float av = accR.x*c0.x + accR.y*c0.y + accR.z*c0.z + accR.w*c0.w
             + accA.x*c1.x + accA.y*c1.y + accA.z*c1.z + accA.w*c1.w;
    float bv = accR.x*c2.x + accR.y*c2.y + accR.z*c2.z + accR.w*c2.w
             + accA.x*c3.x + accA.y*c3.y + accA.z*c3.z + accA.w*c3.w;
    av = sum16(av); bv = sum16(bv);
    if (lane == 0){
      float4* U = (lh < 2) ? UA0 : UA1;
      float4* V = (lh < 2) ? VB0 : VB1;
      ((float*)(U + w))[2 + (lh & 1)] = av;
      ((float*)(V + w))[2 + (lh & 1)] = bv;
    }
  }
  // layer-0 u/v from x0: lane16 p owns dims [8p,8p+8); p<8 head0, p>=8 head1
  {
    int hh = p >> 3;
    int dbase = (8 * p) & 63;
    const float* wvp = eaw + hh * 192;
    float4 u0 = *(const float4*)(wvp + dbase);
    float4 u1 = *(const float4*)(wvp + dbase + 4);
    float4 q0 = *(const float4*)(wvp + 128 + dbase);
    float4 q1 = *(const float4*)(wvp + 128 + dbase + 4);
    float r0 = fmaxf(mx.x,0.f), r1 = fmaxf(mx.y,0.f), r2 = fmaxf(mx.z,0.f), r3 = fmaxf(mx.w,0.f);
    float r4 = fmaxf(my.x,0.f), r5 = fmaxf(my.y,0.f), r6 = fmaxf(my.z,0.f), r7 = fmaxf(my.w,0.f);
    float pu = r0*u0.x + r1*u0.y + r2*u0.z + r3*u0.w
             + r4*u1.x + r5*u1.y + r6*u1.z + r7*u1.w;
    float pv = r0*q0.x + r1*q0.y + r2*q0.z + r3*q0.w
             + r4*q1.x + r5*q1.y + r6*q1.z + r7*q1.w;
    pu = sum8(pu); pv = sum8(pv);
    if (g == 0 && (p == 0 || p == 8)){
      ((float*)(UA0 + w))[hh] = pu;
      ((float*)(VB0 + w))[hh] = pv;
    }
  }
}

// fused edge scores + exp (no global max: exp(s)/Z identical math) + block sums
__global__ void k_se(const int* ee, const int* err,
                     const float4* UA, const float4* VB, const float4* HH,
                     const float* eab_l, const float* cab_l,
                     float* s0, float* s1, float* partials){
  int e = blockIdx.x * blockDim.x + threadIdx.x;
  int tid = threadIdx.x;
  __shared__ float sm0[4], sm1[4];
  float ex0 = 0.f, ex1 = 0.f;
  if (e < EE){
    int2 rc = ((const int2*)ee)[e];
    int2 rr = ((const int2*)err)[e];
    float4 ua = UA[rc.x], vb = VB[rc.y], h1 = HH[rr.x], h2 = HH[rr.y];
    float ea0 = ua.x + 0.5f * (h1.x + h2.x) + vb.x + eab_l[0];
    float ca0 = ua.z + 0.5f * (h1.z + h2.z) + vb.z + cab_l[0];
    ex0 = __expf(leaky(ea0) * leaky(ca0));
    s0[e] = ex0;
    float ea1 = ua.y + 0.5f * (h1.y + h2.y) + vb.y + eab_l[1];
    float ca1 = ua.w + 0.5f * (h1.w + h2.w) + vb.w + cab_l[1];
    ex1 = __expf(leaky(ea1) * leaky(ca1));
    s1[e] = ex1;
  }
  float b0 = wave_sum(ex0), b1 = wave_sum(ex1);
  if ((tid & 63) == 0){ sm0[tid >> 6] = b0; sm1[tid >> 6] = b1; }
  __syncthreads();
  if (tid == 0)  partials[blockIdx.x]      = sm0[0] + sm0[1] + sm0[2] + sm0[3];
  if (tid == 64) partials[PB + blockIdx.x] = sm1[0] + sm1[1] + sm1[2] + sm1[3];
}

// single-block finalize: Z per head
__global__ void k_final(const float* partials, float* scal, int nb){
  __shared__ float sm[1024];
  int tid = threadIdx.x;
  for (int h = 0; h < 2; ++h){
    float v = 0.f;
    for (int i = tid; i < nb; i += 1024) v += partials[h * PB + i];
    sm[tid] = v; __syncthreads();
    for (int s = 512; s; s >>= 1){
      if (tid < s) sm[tid] += sm[tid + s];
      __syncthreads();
    }
    if (tid == 0) scal[h] = sm[0];
    __syncthreads();
  }
}

// segment softmax over p = exp(s)/Z (online pass 1), then group-per-edge PV
// gather with per-lane redundant weight recompute (no cross-lane ops in loop).
// lane16 p owns dims [8p,8p+8); p<8 head0, p>=8 head1. tanh + optional fused
// u/v tables for the NEXT layer.
__global__ void k_agg(const int* ee, const int* ptr, const float* s0, const float* s1,
                      const float* scal, const float* xsrc, float* outp, int ocol,
                      const float* eaw_next, float4* UAn, float4* VBn){
  int w = (blockIdx.x * blockDim.x + threadIdx.x) >> 6;
  int lane = threadIdx.x & 63;
  if (w >= NENT) return;
  int p = lane & 15, g = lane >> 4;
  int beg = ptr[w], end = ptr[w + 1];
  float invZ0 = 1.f / scal[0], invZ1 = 1.f / scal[1];
  float m0 = -INFINITY, m1 = -INFINITY, t0 = 0.f, t1 = 0.f;
  for (int e = beg + lane; e < end; e += 64){
    float q0 = s0[e] * invZ0, q1 = s1[e] * invZ1;
    float n0 = fmaxf(m0, q0); t0 = t0 * __expf(m0 - n0) + __expf(q0 - n0); m0 = n0;
    float n1 = fmaxf(m1, q1); t1 = t1 * __expf(m1 - n1) + __expf(q1 - n1); m1 = n1;
  }
  float M0 = wave_max(m0), M1 = wave_max(m1);
  float z0 = wave_sum((t0 > 0.f) ? t0 * __expf(m0 - M0) : 0.f);
  float z1 = wave_sum((t1 > 0.f) ? t1 * __expf(m1 - M1) : 0.f);
  float iz0 = (z0 > 0.f) ? (1.f / z0) : 0.f;
  float iz1 = (z1 > 0.f) ? (1.f / z1) : 0.f;
  // per-lane head selection (p<8 -> head0 dims 0..63, p>=8 -> head1 dims 64..127)
  const float* ssel = (p < 8) ? s0 : s1;
  float invZs = (p < 8) ? invZ0 : invZ1;
  float Ms    = (p < 8) ? M0 : M1;
  float izs   = (p < 8) ? iz0 : iz1;
  float4 a0 = {0.f,0.f,0.f,0.f}, a1 = {0.f,0.f,0.f,0.f};
  for (int e = beg + g; e < end; e += 4){
    int ce = ((const int2*)ee)[e].y;
    float ws = __expf(ssel[e] * invZs - Ms) * izs;
    const float4* r = (const float4*)(xsrc + (size_t)ce * 384);
    float4 f0 = r[2 * p], f1 = r[2 * p + 1];
    a0.x = fmaf(ws, fmaxf(f0.x, 0.f), a0.x);
    a0.y = fmaf(ws, fmaxf(f0.y, 0.f), a0.y);
    a0.z = fmaf(ws, fmaxf(f0.z, 0.f), a0.z);
    a0.w = fmaf(ws, fmaxf(f0.w, 0.f), a0.w);
    a1.x = fmaf(ws, fmaxf(f1.x, 0.f), a1.x);
    a1.y = fmaf(ws, fmaxf(f1.y, 0.f), a1.y);
    a1.z = fmaf(ws, fmaxf(f1.z, 0.f), a1.z);
    a1.w = fmaf(ws, fmaxf(f1.w, 0.f), a1.w);
  }
  xreduce4(a0, a1);
  float4 o0, o1;
  o0.x = tanhf(a0.x); o0.y = tanhf(a0.y); o0.z = tanhf(a0.z); o0.w = tanhf(a0.w);
  o1.x = tanhf(a1.x); o1.y = tanhf(a1.y); o1.z = tanhf(a1.z); o1.w = tanhf(a1.w);
  if (g == 0){
    ((float4*)(outp + (size_t)w * 384 + ocol))[2 * p]     = o0;
    ((float4*)(outp + (size_t)w * 384 + ocol))[2 * p + 1] = o1;
  }
  if (eaw_next){
    int hh = p >> 3;
    int dbase = (8 * p) & 63;
    const float* wvp = eaw_next + hh * 192;
    float4 u0 = *(const float4*)(wvp + dbase);
    float4 u1 = *(const float4*)(wvp + dbase + 4);
    float4 q0 = *(const float4*)(wvp + 128 + dbase);
    float4 q1 = *(const float4*)(wvp + 128 + dbase + 4);
    float r0 = fmaxf(o0.x,0.f), r1 = fmaxf(o0.y,0.f), r2 = fmaxf(o0.z,0.f), r3 = fmaxf(o0.w,0.f);
    float r4 = fmaxf(o1.x,0.f), r5 = fmaxf(o1.y,0.f), r6 = fmaxf(o1.z,0.f), r7 = fmaxf(o1.w,0.f);
    float pu = r0*u0.x + r1*u0.y + r2*u0.z + r3*u0.w
             + r4*u1.x + r5*u1.y + r6*u1.z + r7*u1.w;
    float pv = r0*q0.x + r1*q0.y + r2*q0.z + r3*q0.w
             + r4*q1.x + r5*q1.y + r6*q1.z + r7*q1.w;
    pu = sum8(pu); pv = sum8(pv);
    if (g == 0 && (p == 0 || p == 8)){
      ((float*)(UAn + w))[hh] = pu;
      ((float*)(VBn + w))[hh] = pv;
    }
  }
}

extern "C" void kernel_launch(void* const* d_in, const int* in_sizes, int n_in,
                              void* d_out, int out_size, void* d_ws, size_t ws_size,
                              hipStream_t stream){
  const float* ent_emb  = (const float*)d_in[0];
  const float* rel_emb  = (const float*)d_in[1];
  const float* attr_emb = (const float*)d_in[2];
  const float* w_r      = (const float*)d_in[3];
  const float* b_r      = (const float*)d_in[4];
  const float* w_a      = (const float*)d_in[5];
  const float* b_a      = (const float*)d_in[6];
  const float* eaw      = (const float*)d_in[7];
  const float* eab      = (const float*)d_in[8];
  const float* caw      = (const float*)d_in[9];
  const float* cab      = (const float*)d_in[10];
  const int*   ee       = (const int*)d_in[11];
  const int*   er_rel2  = (const int*)d_in[13];  // per-ee-edge relation pair (E2)
  const int*   er_idx   = (const int*)d_in[14];
  const int*   ea_idx   = (const int*)d_in[15];
  float* out = (float*)d_out;

  // workspace carve (~7.1 MB)
  int* pee = (int*)d_ws;                 // NENT+1
  int* per = pee + (NENT + 1);
  int* pea = per + (NENT + 1);
  float*  fbase = (float*)d_ws + 150004; // 16B-aligned (600016 % 16 == 0)
  float4* UA0 = (float4*)fbase;          // NENT each
  float4* VB0 = UA0 + NENT;
  float4* UA1 = VB0 + NENT;
  float4* VB1 = UA1 + NENT;
  float4* HH0 = VB1 + NENT;              // RREL each
  float4* HH1 = HH0 + RREL;
  float* s0      = (float*)(HH1 + RREL);
  float* s1      = s0 + EE;
  float* h_rel   = s1 + EE;
  float* h_attr  = h_rel + RREL;
  float* partials= h_attr + AATT;
  float* scal    = partials + 2 * PB;

  const int nb = (EE + 255) / 256;       // 1563 edge blocks
  const int gw = (NENT + 3) / 4;         // wave-per-entity grids

  k_ptr<<<(NENT + 1 + 255) / 256, 256, 0, stream>>>(ee, er_idx, ea_idx, pee, per, pea);
  k_small<<<(AATT + 255) / 256, 256, 0, stream>>>(rel_emb, attr_emb, w_r, w_a, eaw, caw,
                                                  h_rel, h_attr, HH0, HH1);
  k_phase1<<<gw, 256, 0, stream>>>(ent_emb, rel_emb, attr_emb, w_r, b_r, w_a, b_a,
                                   eaw, caw, er_idx, ea_idx, ee, per, pea, pee,
                                   h_rel, h_attr, UA0, VB0, UA1, VB1, out);
  // layer 0
  k_se<<<nb, 256, 0, stream>>>(ee, er_rel2, UA0, VB0, HH0, eab, cab, s0, s1, partials);
  k_final<<<1, 1024, 0, stream>>>(partials, scal, nb);
  k_agg<<<gw, 256, 0, stream>>>(ee, pee, s0, s1, scal, out + 128, out, 0,
                                eaw + 2 * 192, UA1, VB1);
  // layer 1
  k_se<<<nb, 256, 0, stream>>>(ee, er_rel2, UA1, VB1, HH1, eab + 2, cab + 2, s0, s1, partials);
  k_final<<<1, 1024, 0, stream>>>(partials, scal, nb);
  k_agg<<<gw, 256, 0, stream>>>(ee, pee, s0, s1, scal, out, out, 128,
                                (const float*)nullptr, (float4*)nullptr, (float4*)nullptr);
}

// Round 7
// 211.726 us; speedup vs baseline: 1.1371x; 1.1371x over previous
//
#include <hip/hip_runtime.h>
#include <math.h>

#define NENT 50000
#define RREL 2000
#define AATT 5000
#define EE   400000
#define E2   800000
#define EAE  400000
#define PB   2048   // partials stride per head

__device__ __forceinline__ float leaky(float v){ return v > 0.f ? v : 0.3f * v; }

__device__ __forceinline__ float wave_sum(float v){
#pragma unroll
  for (int m = 32; m; m >>= 1) v += __shfl_xor(v, m);
  return v;
}
__device__ __forceinline__ float sum16(float v){
#pragma unroll
  for (int m = 1; m < 16; m <<= 1) v += __shfl_xor(v, m);
  return v;
}
__device__ __forceinline__ float max16(float v){
#pragma unroll
  for (int m = 1; m < 16; m <<= 1) v = fmaxf(v, __shfl_xor(v, m));
  return v;
}
__device__ __forceinline__ float sum8(float v){
#pragma unroll
  for (int m = 1; m < 8; m <<= 1) v += __shfl_xor(v, m);
  return v;
}

__device__ int lowb(const int* a, int n, int key){
  int lo = 0, hi = n;
  while (lo < hi){ int mid = (lo + hi) >> 1; if (a[2 * mid] < key) lo = mid + 1; else hi = mid; }
  return lo;
}

__global__ void k_ptr(const int* ee, const int* er, const int* ea,
                      int* pee, int* per, int* pea){
  int i = blockIdx.x * blockDim.x + threadIdx.x;
  if (i > NENT) return;
  pee[i] = lowb(ee, EE, i);
  per[i] = lowb(er, E2, i);
  pea[i] = lowb(ea, EAE, i);
}

// per-relation/attr scalar tables; HH_l[r] = (hr_h0, hr_h1, hc_h0, hc_h1)
__global__ void k_small(const float* rel_emb, const float* attr_emb,
                        const float* w_r, const float* w_a,
                        const float* eaw, const float* caw,
                        float* h_rel, float* h_attr, float4* HH0, float4* HH1){
  int t = blockIdx.x * blockDim.x + threadIdx.x;
  if (t < RREL){
    const float* e = rel_emb + (size_t)t * 64;
    float s = 0.f;
    for (int k = 0; k < 64; ++k) s += e[k] * w_r[128 + k];
    h_rel[t] = s;
    float hr[4], hc[4];
    for (int lh = 0; lh < 4; ++lh){
      float a = 0.f, c = 0.f;
      for (int k = 0; k < 64; ++k){
        a += e[k] * eaw[lh * 192 + 64 + k];
        c += e[k] * caw[lh * 320 + 128 + k];
      }
      hr[lh] = a; hc[lh] = c;
    }
    HH0[t] = make_float4(hr[0], hr[1], hc[0], hc[1]);
    HH1[t] = make_float4(hr[2], hr[3], hc[2], hc[3]);
  }
  if (t < AATT){
    const float* e = attr_emb + (size_t)t * 64;
    float s = 0.f;
    for (int k = 0; k < 64; ++k) s += e[k] * w_a[128 + k];
    h_attr[t] = s;
  }
}

// GAT concept aggregation, 16-lane group per entity. Pass 1: lane-strided
// (p = lane&15) online max+sum — non-redundant, 1 exp instr per 64 edges
// across the wave's 4 groups. Pass 2: chunk-16, weight per lane, 2 dynamic
// shfls broadcast (obj, wgt) within group, lane p owns dims [4p,4p+4).
__device__ float4 concept_g(float he, const float* h_tab, const int* idx,
                            int beg, int end, const float* emb, int p, int base){
  float m = -INFINITY, t = 0.f;
  for (int e = beg + p; e < end; e += 16){
    float v = leaky(he + h_tab[((const int2*)idx)[e].y]);
    float mn = fmaxf(m, v);
    t = t * __expf(m - mn) + __expf(v - mn);
    m = mn;
  }
  float M = max16(m);
  float z = sum16((t > 0.f) ? t * __expf(m - M) : 0.f);
  float invz = (z > 0.f) ? (1.f / z) : 0.f;
  float4 acc = {0.f, 0.f, 0.f, 0.f};
  for (int c0 = beg; c0 < end; c0 += 16){
    int e = c0 + p;
    int obj = 0; float wgt = 0.f;
    if (e < end){
      obj = ((const int2*)idx)[e].y;
      wgt = __expf(leaky(he + h_tab[obj]) - M) * invz;
    }
    int cnt = end - c0; if (cnt > 16) cnt = 16;
    for (int j = 0; j < cnt; ++j){
      int oj   = __shfl(obj, base | j);
      float wj = __shfl(wgt, base | j);
      float4 f = ((const float4*)(emb + (size_t)oj * 64))[p];
      acc.x = fmaf(wj, f.x, acc.x); acc.y = fmaf(wj, f.y, acc.y);
      acc.z = fmaf(wj, f.z, acc.z); acc.w = fmaf(wj, f.w, acc.w);
    }
  }
  acc.x = fmaxf(acc.x, 0.f); acc.y = fmaxf(acc.y, 0.f);
  acc.z = fmaxf(acc.z, 0.f); acc.w = fmaxf(acc.w, 0.f);
  return acc;
}

// all row-local per-entity work, 16-lane group per entity (4 entities/wave):
// ent dot tables, both concept GATs, mean aggregation, A/B tables, layer-0 u/v.
__global__ void k_phase1(const float* ent_emb, const float* rel_emb, const float* attr_emb,
                         const float* w_r, const float* b_r, const float* w_a, const float* b_a,
                         const float* eaw, const float* caw,
                         const int* er_idx, const int* ea_idx, const int* ee,
                         const int* per, const int* pea, const int* pee,
                         const float* h_rel, const float* h_attr,
                         float4* UA0, float4* VB0, float4* UA1, float4* VB1,
                         float* out){
  int tid = blockIdx.x * blockDim.x + threadIdx.x;
  int lane = threadIdx.x & 63;
  int p = lane & 15, g = lane >> 4, base = lane & 48;
  int w = (tid >> 6) * 4 + g;
  if (w >= NENT) return;
  // her / hea: group dot of own 128-dim ent row with w_r/w_a[0:128)
  const float4* erow = (const float4*)(ent_emb + (size_t)w * 128);
  float4 f0 = erow[2 * p], f1 = erow[2 * p + 1];
  const float4* wr4 = (const float4*)w_r;
  const float4* wa4 = (const float4*)w_a;
  float4 r0 = wr4[2 * p], r1 = wr4[2 * p + 1];
  float4 a0 = wa4[2 * p], a1 = wa4[2 * p + 1];
  float sr = f0.x*r0.x + f0.y*r0.y + f0.z*r0.z + f0.w*r0.w
           + f1.x*r1.x + f1.y*r1.y + f1.z*r1.z + f1.w*r1.w;
  float sa = f0.x*a0.x + f0.y*a0.y + f0.z*a0.z + f0.w*a0.w
           + f1.x*a1.x + f1.y*a1.y + f1.z*a1.z + f1.w*a1.w;
  float heR = sum16(sr) + b_r[0];
  float heA = sum16(sa) + b_a[0];
  // concept aggregations (lane p owns dims [4p,4p+4))
  float4 accR = concept_g(heR, h_rel, er_idx, per[w], per[w + 1], rel_emb, p, base);
  float4 accA = concept_g(heA, h_attr, ea_idx, pea[w], pea[w + 1], attr_emb, p, base);
  ((float4*)(out + (size_t)w * 384 + 256))[p] = accR;
  ((float4*)(out + (size_t)w * 384 + 320))[p] = accA;
  ((float4*)(out + (size_t)NENT * 384 + (size_t)w * 128))[p] = accR;
  ((float4*)(out + (size_t)NENT * 384 + (size_t)w * 128 + 64))[p] = accA;
  // mean neighbor aggregation (512 B ent rows, lane p owns dims [8p,8p+8))
  int beg = pee[w], end = pee[w + 1];
  float4 mx = {0.f,0.f,0.f,0.f}, my = {0.f,0.f,0.f,0.f};
  for (int c0 = beg; c0 < end; c0 += 16){
    int e = c0 + p;
    int col = (e < end) ? ((const int2*)ee)[e].y : 0;
    int cnt = end - c0; if (cnt > 16) cnt = 16;
    for (int j = 0; j < cnt; ++j){
      int cj = __shfl(col, base | j);
      const float4* r = (const float4*)(ent_emb + (size_t)cj * 128);
      float4 q0 = r[2 * p], q1 = r[2 * p + 1];
      mx.x += q0.x; mx.y += q0.y; mx.z += q0.z; mx.w += q0.w;
      my.x += q1.x; my.y += q1.y; my.z += q1.z; my.w += q1.w;
    }
  }
  float invd = 1.f / fmaxf((float)(end - beg), 1.f);
  mx.x *= invd; mx.y *= invd; mx.z *= invd; mx.w *= invd;
  my.x *= invd; my.y *= invd; my.z *= invd; my.w *= invd;
  ((float4*)(out + (size_t)w * 384 + 128))[2 * p]     = mx;
  ((float4*)(out + (size_t)w * 384 + 128))[2 * p + 1] = my;
  // con-attention tables A (row) / B (col) for all 4 (l,h)
#pragma unroll
  for (int lh = 0; lh < 4; ++lh){
    const float* cw = caw + lh * 320;
    float4 c0 = *(const float4*)(cw + 4 * p);
    float4 c1 = *(const float4*)(cw + 64 + 4 * p);
    float4 c2 = *(const float4*)(cw + 192 + 4 * p);
    float4 c3 = *(const float4*)(cw + 256 + 4 * p);
    float av = accR.x*c0.x + accR.y*c0.y + accR.z*c0.z + accR.w*c0.w
             + accA.x*c1.x + accA.y*c1.y + accA.z*c1.z + accA.w*c1.w;
    float bv = accR.x*c2.x + accR.y*c2.y + accR.z*c2.z + accR.w*c2.w
             + accA.x*c3.x + accA.y*c3.y + accA.z*c3.z + accA.w*c3.w;
    av = sum16(av); bv = sum16(bv);
    if (p == 0){
      float4* U = (lh < 2) ? UA0 : UA1;
      float4* V = (lh < 2) ? VB0 : VB1;
      ((float*)(U + w))[2 + (lh & 1)] = av;
      ((float*)(V + w))[2 + (lh & 1)] = bv;
    }
  }
  // layer-0 u/v from x0: lane p owns dims [8p,8p+8); p<8 head0, p>=8 head1
  {
    int hh = p >> 3;
    int dbase = (8 * p) & 63;
    const float* wvp = eaw + hh * 192;
    float4 u0 = *(const float4*)(wvp + dbase);
    float4 u1 = *(const float4*)(wvp + dbase + 4);
    float4 q0 = *(const float4*)(wvp + 128 + dbase);
    float4 q1 = *(const float4*)(wvp + 128 + dbase + 4);
    float e0 = fmaxf(mx.x,0.f), e1 = fmaxf(mx.y,0.f), e2 = fmaxf(mx.z,0.f), e3 = fmaxf(mx.w,0.f);
    float e4 = fmaxf(my.x,0.f), e5 = fmaxf(my.y,0.f), e6 = fmaxf(my.z,0.f), e7 = fmaxf(my.w,0.f);
    float pu = e0*u0.x + e1*u0.y + e2*u0.z + e3*u0.w
             + e4*u1.x + e5*u1.y + e6*u1.z + e7*u1.w;
    float pv = e0*q0.x + e1*q0.y + e2*q0.z + e3*q0.w
             + e4*q1.x + e5*q1.y + e6*q1.z + e7*q1.w;
    pu = sum8(pu); pv = sum8(pv);
    if (p == 0 || p == 8){
      ((float*)(UA0 + w))[hh] = pu;
      ((float*)(VB0 + w))[hh] = pv;
    }
  }
}

// fused edge scores + exp (no global max: exp(s)/Z identical math) + block sums
__global__ void k_se(const int* ee, const int* err,
                     const float4* UA, const float4* VB, const float4* HH,
                     const float* eab_l, const float* cab_l,
                     float* s0, float* s1, float* partials){
  int e = blockIdx.x * blockDim.x + threadIdx.x;
  int tid = threadIdx.x;
  __shared__ float sm0[4], sm1[4];
  float ex0 = 0.f, ex1 = 0.f;
  if (e < EE){
    int2 rc = ((const int2*)ee)[e];
    int2 rr = ((const int2*)err)[e];
    float4 ua = UA[rc.x], vb = VB[rc.y], h1 = HH[rr.x], h2 = HH[rr.y];
    float ea0 = ua.x + 0.5f * (h1.x + h2.x) + vb.x + eab_l[0];
    float ca0 = ua.z + 0.5f * (h1.z + h2.z) + vb.z + cab_l[0];
    ex0 = __expf(leaky(ea0) * leaky(ca0));
    s0[e] = ex0;
    float ea1 = ua.y + 0.5f * (h1.y + h2.y) + vb.y + eab_l[1];
    float ca1 = ua.w + 0.5f * (h1.w + h2.w) + vb.w + cab_l[1];
    ex1 = __expf(leaky(ea1) * leaky(ca1));
    s1[e] = ex1;
  }
  float b0 = wave_sum(ex0), b1 = wave_sum(ex1);
  if ((tid & 63) == 0){ sm0[tid >> 6] = b0; sm1[tid >> 6] = b1; }
  __syncthreads();
  if (tid == 0)  partials[blockIdx.x]      = sm0[0] + sm0[1] + sm0[2] + sm0[3];
  if (tid == 64) partials[PB + blockIdx.x] = sm1[0] + sm1[1] + sm1[2] + sm1[3];
}

// single-block finalize: Z per head
__global__ void k_final(const float* partials, float* scal, int nb){
  __shared__ float sm[1024];
  int tid = threadIdx.x;
  for (int h = 0; h < 2; ++h){
    float v = 0.f;
    for (int i = tid; i < nb; i += 1024) v += partials[h * PB + i];
    sm[tid] = v; __syncthreads();
    for (int s = 512; s; s >>= 1){
      if (tid < s) sm[tid] += sm[tid + s];
      __syncthreads();
    }
    if (tid == 0) scal[h] = sm[0];
    __syncthreads();
  }
}

// segment softmax + PV gather, 16-lane group per entity (4 entities/wave).
// lane p owns output dims [8p,8p+8); p<8 head0, p>=8 head1. Per chunk-16:
// weights per lane (2 exps), 3 dynamic shfls per edge within group.
__global__ void k_agg(const int* ee, const int* ptr, const float* s0, const float* s1,
                      const float* scal, const float* xsrc, float* outp, int ocol,
                      const float* eaw_next, float4* UAn, float4* VBn){
  int tid = blockIdx.x * blockDim.x + threadIdx.x;
  int lane = threadIdx.x & 63;
  int p = lane & 15, base = lane & 48;
  int w = (tid >> 6) * 4 + (lane >> 4);
  if (w >= NENT) return;
  int beg = ptr[w], end = ptr[w + 1];
  float invZ0 = 1.f / scal[0], invZ1 = 1.f / scal[1];
  float m0 = -INFINITY, m1 = -INFINITY, t0 = 0.f, t1 = 0.f;
  for (int e = beg + p; e < end; e += 16){
    float q0 = s0[e] * invZ0, q1 = s1[e] * invZ1;
    float n0 = fmaxf(m0, q0); t0 = t0 * __expf(m0 - n0) + __expf(q0 - n0); m0 = n0;
    float n1 = fmaxf(m1, q1); t1 = t1 * __expf(m1 - n1) + __expf(q1 - n1); m1 = n1;
  }
  float M0 = max16(m0), M1 = max16(m1);
  float z0 = sum16((t0 > 0.f) ? t0 * __expf(m0 - M0) : 0.f);
  float z1 = sum16((t1 > 0.f) ? t1 * __expf(m1 - M1) : 0.f);
  float iz0 = (z0 > 0.f) ? (1.f / z0) : 0.f;
  float iz1 = (z1 > 0.f) ? (1.f / z1) : 0.f;
  float4 a0 = {0.f,0.f,0.f,0.f}, a1 = {0.f,0.f,0.f,0.f};
  for (int c0 = beg; c0 < end; c0 += 16){
    int e = c0 + p;
    int col = 0; float w0 = 0.f, w1 = 0.f;
    if (e < end){
      col = ((const int2*)ee)[e].y;
      w0 = __expf(s0[e] * invZ0 - M0) * iz0;
      w1 = __expf(s1[e] * invZ1 - M1) * iz1;
    }
    int cnt = end - c0; if (cnt > 16) cnt = 16;
    for (int j = 0; j < cnt; ++j){
      int cj    = __shfl(col, base | j);
      float wj0 = __shfl(w0,  base | j);
      float wj1 = __shfl(w1,  base | j);
      const float4* r = (const float4*)(xsrc + (size_t)cj * 384);
      float4 f0 = r[2 * p], f1 = r[2 * p + 1];
      float ws = (p < 8) ? wj0 : wj1;
      a0.x = fmaf(ws, fmaxf(f0.x, 0.f), a0.x);
      a0.y = fmaf(ws, fmaxf(f0.y, 0.f), a0.y);
      a0.z = fmaf(ws, fmaxf(f0.z, 0.f), a0.z);
      a0.w = fmaf(ws, fmaxf(f0.w, 0.f), a0.w);
      a1.x = fmaf(ws, fmaxf(f1.x, 0.f), a1.x);
      a1.y = fmaf(ws, fmaxf(f1.y, 0.f), a1.y);
      a1.z = fmaf(ws, fmaxf(f1.z, 0.f), a1.z);
      a1.w = fmaf(ws, fmaxf(f1.w, 0.f), a1.w);
    }
  }
  float4 o0, o1;
  o0.x = tanhf(a0.x); o0.y = tanhf(a0.y); o0.z = tanhf(a0.z); o0.w = tanhf(a0.w);
  o1.x = tanhf(a1.x); o1.y = tanhf(a1.y); o1.z = tanhf(a1.z); o1.w = tanhf(a1.w);
  ((float4*)(outp + (size_t)w * 384 + ocol))[2 * p]     = o0;
  ((float4*)(outp + (size_t)w * 384 + ocol))[2 * p + 1] = o1;
  if (eaw_next){
    int hh = p >> 3;
    int dbase = (8 * p) & 63;
    const float* wvp = eaw_next + hh * 192;
    float4 u0 = *(const float4*)(wvp + dbase);
    float4 u1 = *(const float4*)(wvp + dbase + 4);
    float4 q0 = *(const float4*)(wvp + 128 + dbase);
    float4 q1 = *(const float4*)(wvp + 128 + dbase + 4);
    float e0 = fmaxf(o0.x,0.f), e1 = fmaxf(o0.y,0.f), e2 = fmaxf(o0.z,0.f), e3 = fmaxf(o0.w,0.f);
    float e4 = fmaxf(o1.x,0.f), e5 = fmaxf(o1.y,0.f), e6 = fmaxf(o1.z,0.f), e7 = fmaxf(o1.w,0.f);
    float pu = e0*u0.x + e1*u0.y + e2*u0.z + e3*u0.w
             + e4*u1.x + e5*u1.y + e6*u1.z + e7*u1.w;
    float pv = e0*q0.x + e1*q0.y + e2*q0.z + e3*q0.w
             + e4*q1.x + e5*q1.y + e6*q1.z + e7*q1.w;
    pu = sum8(pu); pv = sum8(pv);
    if (p == 0 || p == 8){
      ((float*)(UAn + w))[hh] = pu;
      ((float*)(VBn + w))[hh] = pv;
    }
  }
}

extern "C" void kernel_launch(void* const* d_in, const int* in_sizes, int n_in,
                              void* d_out, int out_size, void* d_ws, size_t ws_size,
                              hipStream_t stream){
  const float* ent_emb  = (const float*)d_in[0];
  const float* rel_emb  = (const float*)d_in[1];
  const float* attr_emb = (const float*)d_in[2];
  const float* w_r      = (const float*)d_in[3];
  const float* b_r      = (const float*)d_in[4];
  const float* w_a      = (const float*)d_in[5];
  const float* b_a      = (const float*)d_in[6];
  const float* eaw      = (const float*)d_in[7];
  const float* eab      = (const float*)d_in[8];
  const float* caw      = (const float*)d_in[9];
  const float* cab      = (const float*)d_in[10];
  const int*   ee       = (const int*)d_in[11];
  const int*   er_rel2  = (const int*)d_in[13];  // per-ee-edge relation pair (E2)
  const int*   er_idx   = (const int*)d_in[14];
  const int*   ea_idx   = (const int*)d_in[15];
  float* out = (float*)d_out;

  // workspace carve (~7.1 MB)
  int* pee = (int*)d_ws;                 // NENT+1
  int* per = pee + (NENT + 1);
  int* pea = per + (NENT + 1);
  float*  fbase = (float*)d_ws + 150004; // 16B-aligned (600016 % 16 == 0)
  float4* UA0 = (float4*)fbase;          // NENT each
  float4* VB0 = UA0 + NENT;
  float4* UA1 = VB0 + NENT;
  float4* VB1 = UA1 + NENT;
  float4* HH0 = VB1 + NENT;              // RREL each
  float4* HH1 = HH0 + RREL;
  float* s0      = (float*)(HH1 + RREL);
  float* s1      = s0 + EE;
  float* h_rel   = s1 + EE;
  float* h_attr  = h_rel + RREL;
  float* partials= h_attr + AATT;
  float* scal    = partials + 2 * PB;

  const int nb = (EE + 255) / 256;       // 1563 edge blocks
  const int gq = (NENT + 15) / 16;       // group-per-entity grids (16 ent/block)

  k_ptr<<<(NENT + 1 + 255) / 256, 256, 0, stream>>>(ee, er_idx, ea_idx, pee, per, pea);
  k_small<<<(AATT + 255) / 256, 256, 0, stream>>>(rel_emb, attr_emb, w_r, w_a, eaw, caw,
                                                  h_rel, h_attr, HH0, HH1);
  k_phase1<<<gq, 256, 0, stream>>>(ent_emb, rel_emb, attr_emb, w_r, b_r, w_a, b_a,
                                   eaw, caw, er_idx, ea_idx, ee, per, pea, pee,
                                   h_rel, h_attr, UA0, VB0, UA1, VB1, out);
  // layer 0
  k_se<<<nb, 256, 0, stream>>>(ee, er_rel2, UA0, VB0, HH0, eab, cab, s0, s1, partials);
  k_final<<<1, 1024, 0, stream>>>(partials, scal, nb);
  k_agg<<<gq, 256, 0, stream>>>(ee, pee, s0, s1, scal, out + 128, out, 0,
                                eaw + 2 * 192, UA1, VB1);
  // layer 1
  k_se<<<nb, 256, 0, stream>>>(ee, er_rel2, UA1, VB1, HH1, eab + 2, cab + 2, s0, s1, partials);
  k_final<<<1, 1024, 0, stream>>>(partials, scal, nb);
  k_agg<<<gq, 256, 0, stream>>>(ee, pee, s0, s1, scal, out, out, 128,
                                (const float*)nullptr, (float4*)nullptr, (float4*)nullptr);
}

// Round 8
// 211.273 us; speedup vs baseline: 1.1396x; 1.0021x over previous
//
#include <hip/hip_runtime.h>
#include <math.h>

#define NENT 50000
#define RREL 2000
#define AATT 5000
#define EE   400000
#define E2   800000
#define EAE  400000
#define PB   2048   // partials stride per head

__device__ __forceinline__ float leaky(float v){ return v > 0.f ? v : 0.3f * v; }

__device__ __forceinline__ float wave_sum(float v){
#pragma unroll
  for (int m = 32; m; m >>= 1) v += __shfl_xor(v, m);
  return v;
}
__device__ __forceinline__ float sum16(float v){
#pragma unroll
  for (int m = 1; m < 16; m <<= 1) v += __shfl_xor(v, m);
  return v;
}
__device__ __forceinline__ float sum8(float v){
#pragma unroll
  for (int m = 1; m < 8; m <<= 1) v += __shfl_xor(v, m);
  return v;
}

__device__ int lowb(const int* a, int n, int key){
  int lo = 0, hi = n;
  while (lo < hi){ int mid = (lo + hi) >> 1; if (a[2 * mid] < key) lo = mid + 1; else hi = mid; }
  return lo;
}

__global__ void k_ptr(const int* ee, const int* er, const int* ea,
                      int* pee, int* per, int* pea){
  int i = blockIdx.x * blockDim.x + threadIdx.x;
  if (i > NENT) return;
  pee[i] = lowb(ee, EE, i);
  per[i] = lowb(er, E2, i);
  pea[i] = lowb(ea, EAE, i);
}

// per-relation/attr scalar tables; HH_l[r] = (hr_h0, hr_h1, hc_h0, hc_h1)
__global__ void k_small(const float* rel_emb, const float* attr_emb,
                        const float* w_r, const float* w_a,
                        const float* eaw, const float* caw,
                        float* h_rel, float* h_attr, float4* HH0, float4* HH1){
  int t = blockIdx.x * blockDim.x + threadIdx.x;
  if (t < RREL){
    const float* e = rel_emb + (size_t)t * 64;
    float s = 0.f;
    for (int k = 0; k < 64; ++k) s += e[k] * w_r[128 + k];
    h_rel[t] = s;
    float hr[4], hc[4];
    for (int lh = 0; lh < 4; ++lh){
      float a = 0.f, c = 0.f;
      for (int k = 0; k < 64; ++k){
        a += e[k] * eaw[lh * 192 + 64 + k];
        c += e[k] * caw[lh * 320 + 128 + k];
      }
      hr[lh] = a; hc[lh] = c;
    }
    HH0[t] = make_float4(hr[0], hr[1], hc[0], hc[1]);
    HH1[t] = make_float4(hr[2], hr[3], hc[2], hc[3]);
  }
  if (t < AATT){
    const float* e = attr_emb + (size_t)t * 64;
    float s = 0.f;
    for (int k = 0; k < 64; ++k) s += e[k] * w_a[128 + k];
    h_attr[t] = s;
  }
}

// per-entity dot(ent_emb_row, w[:128]) tables; wave per entity
__global__ void k_ent_tab(const float* ent_emb, const float* w_r, const float* w_a,
                          float* her, float* hea){
  int w = (blockIdx.x * blockDim.x + threadIdx.x) >> 6;
  int lane = threadIdx.x & 63;
  if (w >= NENT) return;
  float2 v = ((const float2*)(ent_emb + (size_t)w * 128))[lane];
  float2 a = ((const float2*)w_r)[lane];
  float2 b = ((const float2*)w_a)[lane];
  float sr = wave_sum(v.x * a.x + v.y * a.y);
  float sa = wave_sum(v.x * b.x + v.y * b.y);
  if (lane == 0){ her[w] = sr; hea[w] = sa; }
}

// edge-parallel concept-attention weights: w[e] = exp(leaky(her[row]+h_tab[obj]+b))
// (segment-max dropped: shift-invariant, scores ~N(0,0.1^2) so exp is safe)
__global__ void k_cw(const int* idx, int ne, const float* het, const float* h_tab,
                     const float* bp, float* wout){
  int e = blockIdx.x * blockDim.x + threadIdx.x;
  if (e >= ne) return;
  int2 rc = ((const int2*)idx)[e];
  wout[e] = __expf(leaky(het[rc.x] + h_tab[rc.y] + bp[0]));
}

// concept aggregation with precomputed weights. 16-lane group per entity.
// Pass1: seg-sum of wq (lane-strided). Pass2: unroll-8, clamp-to-chunk-start
// (duplicate loads hit L1), weight zeroed by cndmask. No shfl/exp in loops.
__device__ float4 concept_g(const float* wq, const int* idx, int beg, int end,
                            const float* emb, int p){
  float t = 0.f;
  for (int e = beg + p; e < end; e += 16) t += wq[e];
  t = sum16(t);
  float invz = (t > 0.f) ? (1.f / t) : 0.f;
  float4 acc = {0.f, 0.f, 0.f, 0.f};
  for (int c0 = beg; c0 < end; c0 += 8){
    int cnt = end - c0; if (cnt > 8) cnt = 8;
#pragma unroll
    for (int j = 0; j < 8; ++j){
      int e = c0 + ((j < cnt) ? j : 0);
      float wgt = wq[e] * invz;
      if (j >= cnt) wgt = 0.f;
      int obj = ((const int2*)idx)[e].y;
      float4 f = ((const float4*)(emb + (size_t)obj * 64))[p];
      acc.x = fmaf(wgt, f.x, acc.x); acc.y = fmaf(wgt, f.y, acc.y);
      acc.z = fmaf(wgt, f.z, acc.z); acc.w = fmaf(wgt, f.w, acc.w);
    }
  }
  acc.x = fmaxf(acc.x, 0.f); acc.y = fmaxf(acc.y, 0.f);
  acc.z = fmaxf(acc.z, 0.f); acc.w = fmaxf(acc.w, 0.f);
  return acc;
}

// row-local per-entity work, 16-lane group per entity (4 entities/wave):
// both concept GATs (precomputed weights), mean aggregation, A/B tables, uv0.
__global__ void k_phase1(const float* ent_emb, const float* rel_emb, const float* attr_emb,
                         const float* eaw, const float* caw,
                         const int* er_idx, const int* ea_idx, const int* ee,
                         const int* per, const int* pea, const int* pee,
                         const float* wr, const float* wa,
                         float4* UA0, float4* VB0, float4* UA1, float4* VB1,
                         float* out){
  int tid = blockIdx.x * blockDim.x + threadIdx.x;
  int lane = threadIdx.x & 63;
  int p = lane & 15;
  int w = (tid >> 6) * 4 + (lane >> 4);
  if (w >= NENT) return;
  // concept aggregations (lane p owns dims [4p,4p+4))
  float4 accR = concept_g(wr, er_idx, per[w], per[w + 1], rel_emb, p);
  float4 accA = concept_g(wa, ea_idx, pea[w], pea[w + 1], attr_emb, p);
  ((float4*)(out + (size_t)w * 384 + 256))[p] = accR;
  ((float4*)(out + (size_t)w * 384 + 320))[p] = accA;
  ((float4*)(out + (size_t)NENT * 384 + (size_t)w * 128))[p] = accR;
  ((float4*)(out + (size_t)NENT * 384 + (size_t)w * 128 + 64))[p] = accA;
  // mean neighbor aggregation (512 B ent rows), unroll-4 with clamp
  int beg = pee[w], end = pee[w + 1];
  float4 mx = {0.f,0.f,0.f,0.f}, my = {0.f,0.f,0.f,0.f};
  for (int c0 = beg; c0 < end; c0 += 4){
    int cnt = end - c0; if (cnt > 4) cnt = 4;
#pragma unroll
    for (int j = 0; j < 4; ++j){
      int e = c0 + ((j < cnt) ? j : 0);
      float msk = (j < cnt) ? 1.f : 0.f;
      int ce = ((const int2*)ee)[e].y;
      const float4* r = (const float4*)(ent_emb + (size_t)ce * 128);
      float4 q0 = r[2 * p], q1 = r[2 * p + 1];
      mx.x = fmaf(msk, q0.x, mx.x); mx.y = fmaf(msk, q0.y, mx.y);
      mx.z = fmaf(msk, q0.z, mx.z); mx.w = fmaf(msk, q0.w, mx.w);
      my.x = fmaf(msk, q1.x, my.x); my.y = fmaf(msk, q1.y, my.y);
      my.z = fmaf(msk, q1.z, my.z); my.w = fmaf(msk, q1.w, my.w);
    }
  }
  float invd = 1.f / fmaxf((float)(end - beg), 1.f);
  mx.x *= invd; mx.y *= invd; mx.z *= invd; mx.w *= invd;
  my.x *= invd; my.y *= invd; my.z *= invd; my.w *= invd;
  ((float4*)(out + (size_t)w * 384 + 128))[2 * p]     = mx;
  ((float4*)(out + (size_t)w * 384 + 128))[2 * p + 1] = my;
  // con-attention tables A (row) / B (col) for all 4 (l,h)
#pragma unroll
  for (int lh = 0; lh < 4; ++lh){
    const float* cw = caw + lh * 320;
    float4 c0 = *(const float4*)(cw + 4 * p);
    float4 c1 = *(const float4*)(cw + 64 + 4 * p);
    float4 c2 = *(const float4*)(cw + 192 + 4 * p);
    float4 c3 = *(const float4*)(cw + 256 + 4 * p);
    float av = accR.x*c0.x + accR.y*c0.y + accR.z*c0.z + accR.w*c0.w
             + accA.x*c1.x + accA.y*c1.y + accA.z*c1.z + accA.w*c1.w;
    float bv = accR.x*c2.x + accR.y*c2.y + accR.z*c2.z + accR.w*c2.w
             + accA.x*c3.x + accA.y*c3.y + accA.z*c3.z + accA.w*c3.w;
    av = sum16(av); bv = sum16(bv);
    if (p == 0){
      float4* U = (lh < 2) ? UA0 : UA1;
      float4* V = (lh < 2) ? VB0 : VB1;
      ((float*)(U + w))[2 + (lh & 1)] = av;
      ((float*)(V + w))[2 + (lh & 1)] = bv;
    }
  }
  // layer-0 u/v from x0: lane p owns dims [8p,8p+8); p<8 head0, p>=8 head1
  {
    int hh = p >> 3;
    int dbase = (8 * p) & 63;
    const float* wvp = eaw + hh * 192;
    float4 u0 = *(const float4*)(wvp + dbase);
    float4 u1 = *(const float4*)(wvp + dbase + 4);
    float4 q0 = *(const float4*)(wvp + 128 + dbase);
    float4 q1 = *(const float4*)(wvp + 128 + dbase + 4);
    float e0 = fmaxf(mx.x,0.f), e1 = fmaxf(mx.y,0.f), e2 = fmaxf(mx.z,0.f), e3 = fmaxf(mx.w,0.f);
    float e4 = fmaxf(my.x,0.f), e5 = fmaxf(my.y,0.f), e6 = fmaxf(my.z,0.f), e7 = fmaxf(my.w,0.f);
    float pu = e0*u0.x + e1*u0.y + e2*u0.z + e3*u0.w
             + e4*u1.x + e5*u1.y + e6*u1.z + e7*u1.w;
    float pv = e0*q0.x + e1*q0.y + e2*q0.z + e3*q0.w
             + e4*q1.x + e5*q1.y + e6*q1.z + e7*q1.w;
    pu = sum8(pu); pv = sum8(pv);
    if (p == 0 || p == 8){
      ((float*)(UA0 + w))[hh] = pu;
      ((float*)(VB0 + w))[hh] = pv;
    }
  }
}

// fused edge scores + exp (no global max) + block sums; s01[e] = {ex0, ex1}
__global__ void k_se(const int* ee, const int* err,
                     const float4* UA, const float4* VB, const float4* HH,
                     const float* eab_l, const float* cab_l,
                     float2* s01, float* partials){
  int e = blockIdx.x * blockDim.x + threadIdx.x;
  int tid = threadIdx.x;
  __shared__ float sm0[4], sm1[4];
  float ex0 = 0.f, ex1 = 0.f;
  if (e < EE){
    int2 rc = ((const int2*)ee)[e];
    int2 rr = ((const int2*)err)[e];
    float4 ua = UA[rc.x], vb = VB[rc.y], h1 = HH[rr.x], h2 = HH[rr.y];
    float ea0 = ua.x + 0.5f * (h1.x + h2.x) + vb.x + eab_l[0];
    float ca0 = ua.z + 0.5f * (h1.z + h2.z) + vb.z + cab_l[0];
    ex0 = __expf(leaky(ea0) * leaky(ca0));
    float ea1 = ua.y + 0.5f * (h1.y + h2.y) + vb.y + eab_l[1];
    float ca1 = ua.w + 0.5f * (h1.w + h2.w) + vb.w + cab_l[1];
    ex1 = __expf(leaky(ea1) * leaky(ca1));
    s01[e] = make_float2(ex0, ex1);
  }
  float b0 = wave_sum(ex0), b1 = wave_sum(ex1);
  if ((tid & 63) == 0){ sm0[tid >> 6] = b0; sm1[tid >> 6] = b1; }
  __syncthreads();
  if (tid == 0)  partials[blockIdx.x]      = sm0[0] + sm0[1] + sm0[2] + sm0[3];
  if (tid == 64) partials[PB + blockIdx.x] = sm1[0] + sm1[1] + sm1[2] + sm1[3];
}

// single-block finalize: Z per head
__global__ void k_final(const float* partials, float* scal, int nb){
  __shared__ float sm[1024];
  int tid = threadIdx.x;
  for (int h = 0; h < 2; ++h){
    float v = 0.f;
    for (int i = tid; i < nb; i += 1024) v += partials[h * PB + i];
    sm[tid] = v; __syncthreads();
    for (int s = 512; s; s >>= 1){
      if (tid < s) sm[tid] += sm[tid + s];
      __syncthreads();
    }
    if (tid == 0) scal[h] = sm[0];
    __syncthreads();
  }
}

// edge-parallel: q = exp(s/Z) in place (segment-max dropped: q args are tiny)
__global__ void k_q(float2* s01, const float* scal){
  int e = blockIdx.x * blockDim.x + threadIdx.x;
  if (e >= EE) return;
  float invZ0 = 1.f / scal[0], invZ1 = 1.f / scal[1];
  float2 s = s01[e];
  s01[e] = make_float2(__expf(s.x * invZ0), __expf(s.y * invZ1));
}

// segment softmax (precomputed q; pass1 = seg-sum) + PV gather, 16-lane group
// per entity. lane p owns dims [8p,8p+8); p<8 head0, p>=8 head1. Pass2:
// unroll-4 with clamp — no exp, no shfl in loops.
__global__ void k_agg(const int* ee, const int* ptr, const float2* q01,
                      const float* xsrc, float* outp, int ocol,
                      const float* eaw_next, float4* UAn, float4* VBn){
  int tid = blockIdx.x * blockDim.x + threadIdx.x;
  int lane = threadIdx.x & 63;
  int p = lane & 15;
  int w = (tid >> 6) * 4 + (lane >> 4);
  if (w >= NENT) return;
  int beg = ptr[w], end = ptr[w + 1];
  float t0 = 0.f, t1 = 0.f;
  for (int e = beg + p; e < end; e += 16){
    float2 q = q01[e];
    t0 += q.x; t1 += q.y;
  }
  t0 = sum16(t0); t1 = sum16(t1);
  float iz0 = (t0 > 0.f) ? (1.f / t0) : 0.f;
  float iz1 = (t1 > 0.f) ? (1.f / t1) : 0.f;
  float izs = (p < 8) ? iz0 : iz1;
  float4 a0 = {0.f,0.f,0.f,0.f}, a1 = {0.f,0.f,0.f,0.f};
  for (int c0 = beg; c0 < end; c0 += 4){
    int cnt = end - c0; if (cnt > 4) cnt = 4;
#pragma unroll
    for (int j = 0; j < 4; ++j){
      int e = c0 + ((j < cnt) ? j : 0);
      float2 q = q01[e];
      float ws = ((p < 8) ? q.x : q.y) * izs;
      if (j >= cnt) ws = 0.f;
      int cj = ((const int2*)ee)[e].y;
      const float4* r = (const float4*)(xsrc + (size_t)cj * 384);
      float4 f0 = r[2 * p], f1 = r[2 * p + 1];
      a0.x = fmaf(ws, fmaxf(f0.x, 0.f), a0.x);
      a0.y = fmaf(ws, fmaxf(f0.y, 0.f), a0.y);
      a0.z = fmaf(ws, fmaxf(f0.z, 0.f), a0.z);
      a0.w = fmaf(ws, fmaxf(f0.w, 0.f), a0.w);
      a1.x = fmaf(ws, fmaxf(f1.x, 0.f), a1.x);
      a1.y = fmaf(ws, fmaxf(f1.y, 0.f), a1.y);
      a1.z = fmaf(ws, fmaxf(f1.z, 0.f), a1.z);
      a1.w = fmaf(ws, fmaxf(f1.w, 0.f), a1.w);
    }
  }
  float4 o0, o1;
  o0.x = tanhf(a0.x); o0.y = tanhf(a0.y); o0.z = tanhf(a0.z); o0.w = tanhf(a0.w);
  o1.x = tanhf(a1.x); o1.y = tanhf(a1.y); o1.z = tanhf(a1.z); o1.w = tanhf(a1.w);
  ((float4*)(outp + (size_t)w * 384 + ocol))[2 * p]     = o0;
  ((float4*)(outp + (size_t)w * 384 + ocol))[2 * p + 1] = o1;
  if (eaw_next){
    int hh = p >> 3;
    int dbase = (8 * p) & 63;
    const float* wvp = eaw_next + hh * 192;
    float4 u0 = *(const float4*)(wvp + dbase);
    float4 u1 = *(const float4*)(wvp + dbase + 4);
    float4 q0 = *(const float4*)(wvp + 128 + dbase);
    float4 q1 = *(const float4*)(wvp + 128 + dbase + 4);
    float e0 = fmaxf(o0.x,0.f), e1 = fmaxf(o0.y,0.f), e2 = fmaxf(o0.z,0.f), e3 = fmaxf(o0.w,0.f);
    float e4 = fmaxf(o1.x,0.f), e5 = fmaxf(o1.y,0.f), e6 = fmaxf(o1.z,0.f), e7 = fmaxf(o1.w,0.f);
    float pu = e0*u0.x + e1*u0.y + e2*u0.z + e3*u0.w
             + e4*u1.x + e5*u1.y + e6*u1.z + e7*u1.w;
    float pv = e0*q0.x + e1*q0.y + e2*q0.z + e3*q0.w
             + e4*q1.x + e5*q1.y + e6*q1.z + e7*q1.w;
    pu = sum8(pu); pv = sum8(pv);
    if (p == 0 || p == 8){
      ((float*)(UAn + w))[hh] = pu;
      ((float*)(VBn + w))[hh] = pv;
    }
  }
}

extern "C" void kernel_launch(void* const* d_in, const int* in_sizes, int n_in,
                              void* d_out, int out_size, void* d_ws, size_t ws_size,
                              hipStream_t stream){
  const float* ent_emb  = (const float*)d_in[0];
  const float* rel_emb  = (const float*)d_in[1];
  const float* attr_emb = (const float*)d_in[2];
  const float* w_r      = (const float*)d_in[3];
  const float* b_r      = (const float*)d_in[4];
  const float* w_a      = (const float*)d_in[5];
  const float* b_a      = (const float*)d_in[6];
  const float* eaw      = (const float*)d_in[7];
  const float* eab      = (const float*)d_in[8];
  const float* caw      = (const float*)d_in[9];
  const float* cab      = (const float*)d_in[10];
  const int*   ee       = (const int*)d_in[11];
  const int*   er_rel2  = (const int*)d_in[13];  // per-ee-edge relation pair (E2)
  const int*   er_idx   = (const int*)d_in[14];
  const int*   ea_idx   = (const int*)d_in[15];
  float* out = (float*)d_out;

  // workspace carve (~9.1 MB)
  int* pee = (int*)d_ws;                 // NENT+1
  int* per = pee + (NENT + 1);
  int* pea = per + (NENT + 1);
  float*  fbase = (float*)d_ws + 150004; // 16B-aligned
  float4* UA0 = (float4*)fbase;          // NENT each
  float4* VB0 = UA0 + NENT;
  float4* UA1 = VB0 + NENT;
  float4* VB1 = UA1 + NENT;
  float4* HH0 = VB1 + NENT;              // RREL each
  float4* HH1 = HH0 + RREL;
  float* her     = (float*)(HH1 + RREL); // NENT
  float* hea     = her + NENT;           // NENT
  float* h_rel   = hea + NENT;           // RREL
  float* h_attr  = h_rel + RREL;         // AATT
  float* partials= h_attr + AATT;        // 2*PB
  float* scal    = partials + 2 * PB;    // 4
  float* wr      = scal + 4;             // E2 floats; ALIASED with s01/q01 (EE float2)
  float* wa      = wr + E2;              // EAE floats
  float2* s01    = (float2*)wr;          // wr dead after k_phase1; k_se runs later

  const int nb = (EE + 255) / 256;       // 1563 edge blocks
  const int gq = (NENT + 15) / 16;       // group-per-entity grids (16 ent/block)
  const int gw = (NENT + 3) / 4;         // wave-per-entity grids

  k_ptr<<<(NENT + 1 + 255) / 256, 256, 0, stream>>>(ee, er_idx, ea_idx, pee, per, pea);
  k_small<<<(AATT + 255) / 256, 256, 0, stream>>>(rel_emb, attr_emb, w_r, w_a, eaw, caw,
                                                  h_rel, h_attr, HH0, HH1);
  k_ent_tab<<<gw, 256, 0, stream>>>(ent_emb, w_r, w_a, her, hea);
  k_cw<<<(E2 + 255) / 256, 256, 0, stream>>>(er_idx, E2, her, h_rel, b_r, wr);
  k_cw<<<(EAE + 255) / 256, 256, 0, stream>>>(ea_idx, EAE, hea, h_attr, b_a, wa);
  k_phase1<<<gq, 256, 0, stream>>>(ent_emb, rel_emb, attr_emb, eaw, caw,
                                   er_idx, ea_idx, ee, per, pea, pee, wr, wa,
                                   UA0, VB0, UA1, VB1, out);
  // layer 0
  k_se<<<nb, 256, 0, stream>>>(ee, er_rel2, UA0, VB0, HH0, eab, cab, s01, partials);
  k_final<<<1, 1024, 0, stream>>>(partials, scal, nb);
  k_q<<<nb, 256, 0, stream>>>(s01, scal);
  k_agg<<<gq, 256, 0, stream>>>(ee, pee, s01, out + 128, out, 0,
                                eaw + 2 * 192, UA1, VB1);
  // layer 1
  k_se<<<nb, 256, 0, stream>>>(ee, er_rel2, UA1, VB1, HH1, eab + 2, cab + 2, s01, partials);
  k_final<<<1, 1024, 0, stream>>>(partials, scal, nb);
  k_q<<<nb, 256, 0, stream>>>(s01, scal);
  k_agg<<<gq, 256, 0, stream>>>(ee, pee, s01, out, out, 128,
                                (const float*)nullptr, (float4*)nullptr, (float4*)nullptr);
}